// Round 8
// baseline (72.716 us; speedup 1.0000x reference)
//
#include <hip/hip_runtime.h>
#include <hip/hip_bf16.h>
#include <cmath>

// Problem constants
#define BB 128
#define MM 64
#define DD 64
#define PP 1024
#define AN 21
#define W1P 68                          // padded LDS row stride (k1)
#define UVP 68                          // padded u/v LDS row stride (k2)

typedef __attribute__((ext_vector_type(8))) short bf16x8;   // 8 bf16 = 4 VGPRs
typedef __attribute__((ext_vector_type(4))) float f32x4;    // MFMA C/D

// tanh-approx GELU via HW transcendentals (~7 VALU + 2 trans).
__device__ __forceinline__ float gelu_fast(float x) {
    const float x2 = x * x;
    const float p = fmaf(0.044715f * x2, x, x);        // x + 0.044715 x^3
    const float z = __builtin_amdgcn_exp2f(2.3022150322f * p);  // exp(2c*p)
    const float r = __builtin_amdgcn_rcpf(z + 1.0f);
    const float th = fmaf(-2.0f, r, 1.0f);             // tanh(c*p)
    const float hx = 0.5f * x;
    return fmaf(hx, th, hx);                           // 0.5x(1+tanh)
}

// RNE float -> bf16 bits (values finite)
__device__ __forceinline__ unsigned short f2bf(float x) {
    union { float f; unsigned u; } c; c.f = x;
    unsigned r = c.u + 0x7fffu + ((c.u >> 16) & 1u);
    return (unsigned short)(r >> 16);
}

// pack 2 floats -> 1 u32 of 2 bf16 (emits v_cvt_pk_bf16_f32)
__device__ __forceinline__ unsigned pk2bf(float lo, float hi) {
    __hip_bfloat162 t = __float22bfloat162_rn(make_float2(lo, hi));
    unsigned u; __builtin_memcpy(&u, &t, 4);
    return u;
}

// butterfly sum over each 16-lane row via DPP (xor 1,2,4,8)
__device__ __forceinline__ float row_sum16(float x) {
    int t;
    t = __builtin_amdgcn_update_dpp(0, __float_as_int(x), 0xB1, 0xF, 0xF, true); // xor1
    x += __int_as_float(t);
    t = __builtin_amdgcn_update_dpp(0, __float_as_int(x), 0x4E, 0xF, 0xF, true); // xor2
    x += __int_as_float(t);
    t = __builtin_amdgcn_update_dpp(0, __float_as_int(x), 0x141, 0xF, 0xF, true); // xor4
    x += __int_as_float(t);
    t = __builtin_amdgcn_update_dpp(0, __float_as_int(x), 0x140, 0xF, 0xF, true); // xor8
    x += __int_as_float(t);
    return x;
}

// ---------------------------------------------------------------------------
// Kernel 1 (FROZEN): u = e@W1[:64]+b1, v = e@W1[64:]; W1 transposed+padded
// in LDS; b1 folded into u; first 16 blocks emit W2T; zeroes out diagonal.
// ---------------------------------------------------------------------------
__global__ __launch_bounds__(256) void k_embed_uv(
    const int* __restrict__ positions, const int* __restrict__ amino,
    const float* __restrict__ pos_table, const float* __restrict__ aa_table,
    const float* __restrict__ W1, const float* __restrict__ W2,
    const float* __restrict__ b1,
    float* __restrict__ u, float* __restrict__ v,
    unsigned short* __restrict__ w2t, float* __restrict__ out)
{
    __shared__ __align__(16) float w1u[DD][W1P];
    __shared__ __align__(16) float w1v[DD][W1P];
    __shared__ __align__(16) float es[4][DD];
    const int wave = threadIdx.x >> 6;
    const int lane = threadIdx.x & 63;

    {
        const float4* W14 = (const float4*)W1;
#pragma unroll
        for (int it = 0; it < 8; ++it) {
            const int n = it * 256 + threadIdx.x;
            const int k = n >> 4;
            const int c4 = (n & 15) << 2;
            const float4 w = W14[n];
            if (k < DD) {
                w1u[c4 + 0][k] = w.x; w1u[c4 + 1][k] = w.y;
                w1u[c4 + 2][k] = w.z; w1u[c4 + 3][k] = w.w;
            } else {
                w1v[c4 + 0][k - DD] = w.x; w1v[c4 + 1][k - DD] = w.y;
                w1v[c4 + 2][k - DD] = w.z; w1v[c4 + 3][k - DD] = w.w;
            }
        }
    }
    if (blockIdx.x < 16) {
        const int n = blockIdx.x * 256 + threadIdx.x;
        w2t[(n & 63) * DD + (n >> 6)] = f2bf(W2[n]);
    }
    const float b1l = b1[lane];
    __syncthreads();

#pragma unroll
    for (int tt = 0; tt < 4; ++tt) {
        const int idx = blockIdx.x * 16 + wave * 4 + tt;   // b*M + m
        int p = positions[idx];
        p = p < 0 ? 0 : (p > PP - 1 ? PP - 1 : p);
        int a = amino[idx];
        a = a < 0 ? 0 : (a > AN - 1 ? AN - 1 : a);

        const float e = pos_table[p * DD + lane] + aa_table[a * DD + lane];
        asm volatile("s_waitcnt lgkmcnt(0)" ::: "memory");
        es[wave][lane] = e;
        asm volatile("s_waitcnt lgkmcnt(0)" ::: "memory");

        float uacc = 0.0f, vacc = 0.0f;
#pragma unroll
        for (int k4 = 0; k4 < DD / 4; ++k4) {
            const float4 ek = *(const float4*)&es[wave][k4 * 4];
            const float4 wu = *(const float4*)&w1u[lane][k4 * 4];
            const float4 wv = *(const float4*)&w1v[lane][k4 * 4];
            uacc = fmaf(ek.x, wu.x, uacc); uacc = fmaf(ek.y, wu.y, uacc);
            uacc = fmaf(ek.z, wu.z, uacc); uacc = fmaf(ek.w, wu.w, uacc);
            vacc = fmaf(ek.x, wv.x, vacc); vacc = fmaf(ek.y, wv.y, vacc);
            vacc = fmaf(ek.z, wv.z, vacc); vacc = fmaf(ek.w, wv.w, vacc);
        }
        u[idx * DD + lane] = uacc + b1l;
        v[idx * DD + lane] = vacc;

        if (lane == 0) {
            const int b = idx >> 6, m = idx & 63;
            out[b * MM * MM + m * MM + m] = 0.0f;
        }
    }
}

// ---------------------------------------------------------------------------
// Kernel 2 (round-6 structure, REVERTED from round 7's regression), as a
// template<REP>. REP=1 is the production kernel. REP=3 is an INSTRUMENTATION
// launch: re-executes the whole compute/store phase 3x with identical results
// (idempotent stores; the later REP=1 launch rewrites the same bytes), making
// a single ~75-80us dispatch whose rocprof row (VALUBusy/MfmaUtil/VGPR/
// conflicts) surfaces above the harness's 40us fill dispatches in top-5 --
// the pair-MLP counters have been invisible since round 4.
// ---------------------------------------------------------------------------
template <int REP>
__global__ __launch_bounds__(256) void k_pair_mfma(
    const float* __restrict__ u, const float* __restrict__ v,
    const unsigned short* __restrict__ w2t,
    const float* __restrict__ b2, const float* __restrict__ W3,
    const float* __restrict__ b3, float* __restrict__ out)
{
    __shared__ __align__(16) float us[16][UVP];
    __shared__ __align__(16) float vs[16][UVP];
    const int lane = threadIdx.x & 63;
    const int wave = threadIdx.x >> 6;
    const int r = lane & 15;        // A row (build) / C col (output)
    const int g = lane >> 4;

    const int blk = blockIdx.x;     // 0..9
    const int b   = blockIdx.y;     // 0..127
    // packed (ib, jb) tables: blocks {01,02,03,12,13,23, 00,11,22,33}
    const int ib = (0x1A211200u >> (3 * blk)) & 7;
    const int jb = (0x1A21B4D1u >> (3 * blk)) & 7;
    const bool diag = (blk >= 6);

    // coalesced stage: 16 rows x 64 floats each of u and v
    {
        const int row = threadIdx.x >> 4;
        const int q   = threadIdx.x & 15;
        const float4 uq = *(const float4*)(u + ((b * MM + ib * 16 + row) * DD) + q * 4);
        const float4 vq = *(const float4*)(v + ((b * MM + jb * 16 + row) * DD) + q * 4);
        *(float4*)&us[row][q * 4] = uq;
        *(float4*)&vs[row][q * 4] = vq;
    }

    bf16x8 bfr[2][4];               // B frag: W2[k=kh*32+g*8+e][n=cb*16+r]
#pragma unroll
    for (int kh = 0; kh < 2; ++kh)
#pragma unroll
        for (int cb = 0; cb < 4; ++cb)
            bfr[kh][cb] = *(const bf16x8*)(w2t + ((cb * 16 + r) * DD + kh * 32 + g * 8));
    float b2f[4], w3f[4];
#pragma unroll
    for (int cb = 0; cb < 4; ++cb) {
        b2f[cb] = b2[cb * 16 + r];
        w3f[cb] = W3[cb * 16 + r];
    }
    const float b3s = b3[0];

    __syncthreads();

    float* __restrict__ ob = out + b * (MM * MM);
    const int i0 = ib * 16;

    for (int rep = 0; rep < REP; ++rep) {
#pragma unroll
        for (int tt = 0; tt < 4; ++tt) {
            const int pj = tt * 4 + wave;            // column within block
            const int jg = jb * 16 + pj;             // global j

            // ---- layer 1: A frags from LDS ----
            bf16x8 afr[2];
#pragma unroll
            for (int kh = 0; kh < 2; ++kh) {
                const int koff = kh * 32 + g * 8;
                const float4 u0 = *(const float4*)&us[r][koff];
                const float4 u1 = *(const float4*)&us[r][koff + 4];
                const float4 v0 = *(const float4*)&vs[pj][koff];
                const float4 v1 = *(const float4*)&vs[pj][koff + 4];
                float x[8];
                x[0] = u0.x + v0.x; x[1] = u0.y + v0.y; x[2] = u0.z + v0.z; x[3] = u0.w + v0.w;
                x[4] = u1.x + v1.x; x[5] = u1.y + v1.y; x[6] = u1.z + v1.z; x[7] = u1.w + v1.w;
                unsigned w0 = pk2bf(gelu_fast(x[0]), gelu_fast(x[1]));
                unsigned w1 = pk2bf(gelu_fast(x[2]), gelu_fast(x[3]));
                unsigned w2 = pk2bf(gelu_fast(x[4]), gelu_fast(x[5]));
                unsigned w3 = pk2bf(gelu_fast(x[6]), gelu_fast(x[7]));
                union { bf16x8 v8; unsigned u4[4]; } cvt;
                cvt.u4[0] = w0; cvt.u4[1] = w1; cvt.u4[2] = w2; cvt.u4[3] = w3;
                afr[kh] = cvt.v8;
            }

            // ---- layer 2: 8 MFMAs ----
            f32x4 acc[4];
#pragma unroll
            for (int cb = 0; cb < 4; ++cb) {
                f32x4 z = {0.0f, 0.0f, 0.0f, 0.0f};
                z = __builtin_amdgcn_mfma_f32_16x16x32_bf16(afr[0], bfr[0][cb], z, 0, 0, 0);
                acc[cb] = __builtin_amdgcn_mfma_f32_16x16x32_bf16(afr[1], bfr[1][cb], z, 0, 0, 0);
            }

            // ---- layer 3: gelu + W3 dot, DPP row-sum ----
            float s0, s1, s2, s3;
            {
                float a0 = 0, a1 = 0, a2 = 0, a3 = 0;
#pragma unroll
                for (int cb = 0; cb < 4; ++cb) {
                    a0 = fmaf(gelu_fast(acc[cb][0] + b2f[cb]), w3f[cb], a0);
                    a1 = fmaf(gelu_fast(acc[cb][1] + b2f[cb]), w3f[cb], a1);
                    a2 = fmaf(gelu_fast(acc[cb][2] + b2f[cb]), w3f[cb], a2);
                    a3 = fmaf(gelu_fast(acc[cb][3] + b2f[cb]), w3f[cb], a3);
                }
                s0 = row_sum16(a0) + b3s;
                s1 = row_sum16(a1) + b3s;
                s2 = row_sum16(a2) + b3s;
                s3 = row_sum16(a3) + b3s;
            }

            if (r < 4) {
                const int p = g * 4 + r;             // local pair (C row)
                if (!diag || p < pj) {
                    const float sc = (r == 0) ? s0 : (r == 1) ? s1 : (r == 2) ? s2 : s3;
                    const int ig = i0 + p;
                    ob[ig * MM + jg] = sc;           // column (scattered)
                    ob[jg * MM + ig] = sc;           // mirror row (coalesced)
                }
            }
        }
    }
}

extern "C" void kernel_launch(void* const* d_in, const int* in_sizes, int n_in,
                              void* d_out, int out_size, void* d_ws, size_t ws_size,
                              hipStream_t stream) {
    const int*   positions = (const int*)  d_in[0];
    const int*   amino     = (const int*)  d_in[1];
    const float* pos_table = (const float*)d_in[2];
    const float* aa_table  = (const float*)d_in[3];
    const float* W1        = (const float*)d_in[4];
    const float* b1        = (const float*)d_in[5];
    const float* W2        = (const float*)d_in[6];
    const float* b2        = (const float*)d_in[7];
    const float* W3        = (const float*)d_in[8];
    const float* b3        = (const float*)d_in[9];
    float* out = (float*)d_out;

    float* u = (float*)d_ws;                              // [B*M, 64] (2 MB), b1 folded
    float* v = u + (size_t)BB * MM * DD;                  // [B*M, 64] (2 MB)
    unsigned short* w2t = (unsigned short*)(v + (size_t)BB * MM * DD);  // 8 KB bf16

    // K1 (frozen): 8192 tokens, 16/block -> 512 blocks (+ folded w2t prep)
    k_embed_uv<<<512, 256, 0, stream>>>(positions, amino, pos_table, aa_table,
                                        W1, W2, b1, u, v, w2t, out);
    // INSTRUMENTATION: 3x-compute replica of k2 (idempotent; overwritten by
    // the production launch below). Its ~75-80us dispatch surfaces the pair-
    // MLP counters above the 40us harness fills in rocprof top-5.
    k_pair_mfma<3><<<dim3(10, 128), 256, 0, stream>>>(u, v, w2t, b2, W3, b3, out);
    // Production k2 (round-6 structure, round-7 tiling reverted)
    k_pair_mfma<1><<<dim3(10, 128), 256, 0, stream>>>(u, v, w2t, b2, W3, b3, out);
}

// Round 9
// 30.304 us; speedup vs baseline: 2.3995x; 2.3995x over previous
//
#include <hip/hip_runtime.h>
#include <hip/hip_bf16.h>
#include <cmath>

// Problem constants
#define BB 128
#define MM 64
#define DD 64
#define PP 1024
#define AN 21
#define UVP 68                          // padded u/v LDS row stride (k2)

typedef __attribute__((ext_vector_type(8))) short bf16x8;   // 8 bf16 = 4 VGPRs
typedef __attribute__((ext_vector_type(4))) float f32x4;    // MFMA C/D

// tanh-approx GELU, 7 issue slots (2 of them trans):
// gelu = 0.5x(1+tanh(c(x+0.044715x^3))) = x - x*rcp(exp2(2c*log2e*p)+1)
// (identity: hx(1+th) with th=1-2r  ==  x - x*r; saves 2 VALU vs round 8)
__device__ __forceinline__ float gelu_fast(float x) {
    const float p = fmaf(0.044715f * x * x, x, x);              // mul, fma
    const float z = __builtin_amdgcn_exp2f(2.3022150322f * p);  // mul, exp2
    const float r = __builtin_amdgcn_rcpf(z + 1.0f);            // add, rcp
    return fmaf(-x, r, x);                                      // fma
}

// RNE float -> bf16 bits (values finite)
__device__ __forceinline__ unsigned short f2bf(float x) {
    union { float f; unsigned u; } c; c.f = x;
    unsigned r = c.u + 0x7fffu + ((c.u >> 16) & 1u);
    return (unsigned short)(r >> 16);
}

// pack 2 floats -> 1 u32 of 2 bf16 (emits v_cvt_pk_bf16_f32)
__device__ __forceinline__ unsigned pk2bf(float lo, float hi) {
    __hip_bfloat162 t = __float22bfloat162_rn(make_float2(lo, hi));
    unsigned u; __builtin_memcpy(&u, &t, 4);
    return u;
}

// butterfly sum over each 16-lane row via DPP (xor 1,2,4,8)
__device__ __forceinline__ float row_sum16(float x) {
    int t;
    t = __builtin_amdgcn_update_dpp(0, __float_as_int(x), 0xB1, 0xF, 0xF, true); // xor1
    x += __int_as_float(t);
    t = __builtin_amdgcn_update_dpp(0, __float_as_int(x), 0x4E, 0xF, 0xF, true); // xor2
    x += __int_as_float(t);
    t = __builtin_amdgcn_update_dpp(0, __float_as_int(x), 0x141, 0xF, 0xF, true); // xor4
    x += __int_as_float(t);
    t = __builtin_amdgcn_update_dpp(0, __float_as_int(x), 0x140, 0xF, 0xF, true); // xor8
    x += __int_as_float(t);
    return x;
}

// ---------------------------------------------------------------------------
// Kernel 1 (MFMA rewrite): u = e@W1[:64] + b1, v = e@W1[64:].
// Round-8 counters showed the old k1 was LDS-BW-bound (~5us: 48 ds_read_b128
// per lane per token). This version has ZERO LDS: W1 B-frags built once per
// wave from L1-hot scalar loads (bf16), e gathered per-lane from the tables,
// 16 MFMAs per 16-token tile, b1 added post-MFMA in f32.
// 256 blocks x 64 threads (1 wave), 2 token-tiles per wave.
// Numerics: bf16 e/W1 adds ~4e-3 to the final output (threshold 5.1e-2).
// Blocks 0..63 also emit W2T (bf16 transposed) for k2. Zeroes out diagonal.
// ---------------------------------------------------------------------------
__global__ __launch_bounds__(64) void k_embed_uv(
    const int* __restrict__ positions, const int* __restrict__ amino,
    const float* __restrict__ pos_table, const float* __restrict__ aa_table,
    const float* __restrict__ W1, const float* __restrict__ W2,
    const float* __restrict__ b1,
    float* __restrict__ u, float* __restrict__ v,
    unsigned short* __restrict__ w2t, float* __restrict__ out)
{
    const int lane = threadIdx.x;
    const int r = lane & 15;        // A row (token) / C col (out feature)
    const int g = lane >> 4;        // k-group

    // folded w2t prep: 4096 elems over blocks 0..63
    if (blockIdx.x < 64) {
        const int n = blockIdx.x * 64 + lane;
        w2t[(n & 63) * DD + (n >> 6)] = f2bf(W2[n]);
    }

    // ---- B-frags from W1 (row-major [kin][out]); L1-hot scalar loads ----
    // w1f[uv][kh][cb]: lane (g,r) holds W1[uv*64 + kh*32 + g*8 + e][cb*16 + r]
    bf16x8 w1f[2][2][4];
#pragma unroll
    for (int uv = 0; uv < 2; ++uv)
#pragma unroll
        for (int kh = 0; kh < 2; ++kh) {
            const int k0 = uv * 64 + kh * 32 + g * 8;
#pragma unroll
            for (int cb = 0; cb < 4; ++cb) {
                const float* src = W1 + k0 * DD + cb * 16 + r;
                float t[8];
#pragma unroll
                for (int e = 0; e < 8; ++e) t[e] = src[e * DD];
                union { bf16x8 v8; unsigned u4[4]; } cvt;
                cvt.u4[0] = pk2bf(t[0], t[1]); cvt.u4[1] = pk2bf(t[2], t[3]);
                cvt.u4[2] = pk2bf(t[4], t[5]); cvt.u4[3] = pk2bf(t[6], t[7]);
                w1f[uv][kh][cb] = cvt.v8;
            }
        }
    float b1f[4];
#pragma unroll
    for (int cb = 0; cb < 4; ++cb) b1f[cb] = b1[cb * 16 + r];

#pragma unroll
    for (int t = 0; t < 2; ++t) {
        const int t0 = (blockIdx.x * 2 + t) * 16;    // tile token base
        const int tok = t0 + r;                      // this lane's A-row token
        int p = positions[tok];
        p = p < 0 ? 0 : (p > PP - 1 ? PP - 1 : p);
        int a = amino[tok];
        a = a < 0 ? 0 : (a > AN - 1 ? AN - 1 : a);

        // ---- A-frags: e[tok][k], k = kh*32 + g*8 + e, bf16 ----
        bf16x8 ef[2];
#pragma unroll
        for (int kh = 0; kh < 2; ++kh) {
            const int koff = kh * 32 + g * 8;
            const float4 p0 = *(const float4*)(pos_table + p * DD + koff);
            const float4 p1 = *(const float4*)(pos_table + p * DD + koff + 4);
            const float4 a0 = *(const float4*)(aa_table + a * DD + koff);
            const float4 a1 = *(const float4*)(aa_table + a * DD + koff + 4);
            union { bf16x8 v8; unsigned u4[4]; } cvt;
            cvt.u4[0] = pk2bf(p0.x + a0.x, p0.y + a0.y);
            cvt.u4[1] = pk2bf(p0.z + a0.z, p0.w + a0.w);
            cvt.u4[2] = pk2bf(p1.x + a1.x, p1.y + a1.y);
            cvt.u4[3] = pk2bf(p1.z + a1.z, p1.w + a1.w);
            ef[kh] = cvt.v8;
        }

        // ---- 16 MFMAs: u and v, 4 col-blocks x 2 k-halves ----
#pragma unroll
        for (int uv = 0; uv < 2; ++uv) {
            float* __restrict__ dst = uv ? v : u;
#pragma unroll
            for (int cb = 0; cb < 4; ++cb) {
                f32x4 z = {0.0f, 0.0f, 0.0f, 0.0f};
                z = __builtin_amdgcn_mfma_f32_16x16x32_bf16(ef[0], w1f[uv][0][cb], z, 0, 0, 0);
                z = __builtin_amdgcn_mfma_f32_16x16x32_bf16(ef[1], w1f[uv][1][cb], z, 0, 0, 0);
                const float badd = uv ? 0.0f : b1f[cb];
                // C/D: row = g*4+reg (token), col = cb*16+r (feature)
#pragma unroll
                for (int reg = 0; reg < 4; ++reg)
                    dst[(t0 + g * 4 + reg) * DD + cb * 16 + r] = z[reg] + badd;
            }
        }

        // diagonal zero: one lane group covers the tile's 16 tokens
        if (g == 0) {
            const int b = tok >> 6, m = tok & 63;
            out[b * MM * MM + m * MM + m] = 0.0f;
        }
    }
}

// ---------------------------------------------------------------------------
// Kernel 2 (round-6 structure, production): workgroup = (blk, b) 16x16 pair
// block; blk 0..5 strictly-upper, 6..9 diagonal (p<pj masked). u/v rows
// staged coalesced in LDS; A-frags built in-register with 7-slot gelu;
// 8 MFMAs; layer-3 gelu + W3 dot + DPP row-sum; mirrored store.
// ---------------------------------------------------------------------------
__global__ __launch_bounds__(256) void k_pair_mfma(
    const float* __restrict__ u, const float* __restrict__ v,
    const unsigned short* __restrict__ w2t,
    const float* __restrict__ b2, const float* __restrict__ W3,
    const float* __restrict__ b3, float* __restrict__ out)
{
    __shared__ __align__(16) float us[16][UVP];
    __shared__ __align__(16) float vs[16][UVP];
    const int lane = threadIdx.x & 63;
    const int wave = threadIdx.x >> 6;
    const int r = lane & 15;        // A row (build) / C col (output)
    const int g = lane >> 4;

    const int blk = blockIdx.x;     // 0..9
    const int b   = blockIdx.y;     // 0..127
    // packed (ib, jb) tables: blocks {01,02,03,12,13,23, 00,11,22,33}
    const int ib = (0x1A211200u >> (3 * blk)) & 7;
    const int jb = (0x1A21B4D1u >> (3 * blk)) & 7;
    const bool diag = (blk >= 6);

    // coalesced stage: 16 rows x 64 floats each of u and v
    {
        const int row = threadIdx.x >> 4;
        const int q   = threadIdx.x & 15;
        const float4 uq = *(const float4*)(u + ((b * MM + ib * 16 + row) * DD) + q * 4);
        const float4 vq = *(const float4*)(v + ((b * MM + jb * 16 + row) * DD) + q * 4);
        *(float4*)&us[row][q * 4] = uq;
        *(float4*)&vs[row][q * 4] = vq;
    }

    bf16x8 bfr[2][4];               // B frag: W2[k=kh*32+g*8+e][n=cb*16+r]
#pragma unroll
    for (int kh = 0; kh < 2; ++kh)
#pragma unroll
        for (int cb = 0; cb < 4; ++cb)
            bfr[kh][cb] = *(const bf16x8*)(w2t + ((cb * 16 + r) * DD + kh * 32 + g * 8));
    float b2f[4], w3f[4];
#pragma unroll
    for (int cb = 0; cb < 4; ++cb) {
        b2f[cb] = b2[cb * 16 + r];
        w3f[cb] = W3[cb * 16 + r];
    }
    const float b3s = b3[0];

    __syncthreads();

    float* __restrict__ ob = out + b * (MM * MM);
    const int i0 = ib * 16;

#pragma unroll
    for (int tt = 0; tt < 4; ++tt) {
        const int pj = tt * 4 + wave;            // column within block
        const int jg = jb * 16 + pj;             // global j

        // ---- layer 1: A frags from LDS ----
        bf16x8 afr[2];
#pragma unroll
        for (int kh = 0; kh < 2; ++kh) {
            const int koff = kh * 32 + g * 8;
            const float4 u0 = *(const float4*)&us[r][koff];
            const float4 u1 = *(const float4*)&us[r][koff + 4];
            const float4 v0 = *(const float4*)&vs[pj][koff];
            const float4 v1 = *(const float4*)&vs[pj][koff + 4];
            float x[8];
            x[0] = u0.x + v0.x; x[1] = u0.y + v0.y; x[2] = u0.z + v0.z; x[3] = u0.w + v0.w;
            x[4] = u1.x + v1.x; x[5] = u1.y + v1.y; x[6] = u1.z + v1.z; x[7] = u1.w + v1.w;
            unsigned w0 = pk2bf(gelu_fast(x[0]), gelu_fast(x[1]));
            unsigned w1 = pk2bf(gelu_fast(x[2]), gelu_fast(x[3]));
            unsigned w2 = pk2bf(gelu_fast(x[4]), gelu_fast(x[5]));
            unsigned w3 = pk2bf(gelu_fast(x[6]), gelu_fast(x[7]));
            union { bf16x8 v8; unsigned u4[4]; } cvt;
            cvt.u4[0] = w0; cvt.u4[1] = w1; cvt.u4[2] = w2; cvt.u4[3] = w3;
            afr[kh] = cvt.v8;
        }

        // ---- layer 2: 8 MFMAs ----
        f32x4 acc[4];
#pragma unroll
        for (int cb = 0; cb < 4; ++cb) {
            f32x4 z = {0.0f, 0.0f, 0.0f, 0.0f};
            z = __builtin_amdgcn_mfma_f32_16x16x32_bf16(afr[0], bfr[0][cb], z, 0, 0, 0);
            acc[cb] = __builtin_amdgcn_mfma_f32_16x16x32_bf16(afr[1], bfr[1][cb], z, 0, 0, 0);
        }

        // ---- layer 3: gelu + W3 dot, DPP row-sum ----
        float s0, s1, s2, s3;
        {
            float a0 = 0, a1 = 0, a2 = 0, a3 = 0;
#pragma unroll
            for (int cb = 0; cb < 4; ++cb) {
                a0 = fmaf(gelu_fast(acc[cb][0] + b2f[cb]), w3f[cb], a0);
                a1 = fmaf(gelu_fast(acc[cb][1] + b2f[cb]), w3f[cb], a1);
                a2 = fmaf(gelu_fast(acc[cb][2] + b2f[cb]), w3f[cb], a2);
                a3 = fmaf(gelu_fast(acc[cb][3] + b2f[cb]), w3f[cb], a3);
            }
            s0 = row_sum16(a0) + b3s;
            s1 = row_sum16(a1) + b3s;
            s2 = row_sum16(a2) + b3s;
            s3 = row_sum16(a3) + b3s;
        }

        if (r < 4) {
            const int p = g * 4 + r;             // local pair (C row)
            if (!diag || p < pj) {
                const float sc = (r == 0) ? s0 : (r == 1) ? s1 : (r == 2) ? s2 : s3;
                const int ig = i0 + p;
                ob[ig * MM + jg] = sc;           // column (scattered)
                ob[jg * MM + ig] = sc;           // mirror row (coalesced)
            }
        }
    }
}

extern "C" void kernel_launch(void* const* d_in, const int* in_sizes, int n_in,
                              void* d_out, int out_size, void* d_ws, size_t ws_size,
                              hipStream_t stream) {
    const int*   positions = (const int*)  d_in[0];
    const int*   amino     = (const int*)  d_in[1];
    const float* pos_table = (const float*)d_in[2];
    const float* aa_table  = (const float*)d_in[3];
    const float* W1        = (const float*)d_in[4];
    const float* b1        = (const float*)d_in[5];
    const float* W2        = (const float*)d_in[6];
    const float* b2        = (const float*)d_in[7];
    const float* W3        = (const float*)d_in[8];
    const float* b3        = (const float*)d_in[9];
    float* out = (float*)d_out;

    float* u = (float*)d_ws;                              // [B*M, 64] (2 MB), b1 folded
    float* v = u + (size_t)BB * MM * DD;                  // [B*M, 64] (2 MB)
    unsigned short* w2t = (unsigned short*)(v + (size_t)BB * MM * DD);  // 8 KB bf16

    // K1 (MFMA): 8192 tokens, 2x16-token tiles per wave -> 256 blocks x 64
    k_embed_uv<<<256, 64, 0, stream>>>(positions, amino, pos_table, aa_table,
                                       W1, W2, b1, u, v, w2t, out);
    // K2: (10 pair-blocks) x (128 batches), 256 threads each
    k_pair_mfma<<<dim3(10, 128), 256, 0, stream>>>(u, v, w2t, b2, W3, b3, out);
}

// Round 10
// 28.235 us; speedup vs baseline: 2.5754x; 1.0733x over previous
//
#include <hip/hip_runtime.h>
#include <hip/hip_bf16.h>
#include <cmath>

// Problem constants
#define BB 128
#define MM 64
#define DD 64
#define PP 1024
#define AN 21
#define UVP 68                          // padded u/v LDS row stride

typedef __attribute__((ext_vector_type(8))) short bf16x8;   // 8 bf16 = 4 VGPRs
typedef __attribute__((ext_vector_type(4))) float f32x4;    // MFMA C/D

// tanh-approx GELU, 7 issue slots (2 trans):
// gelu = x - x*rcp(exp2(2c*log2e*(x+0.044715x^3)) + 1)
__device__ __forceinline__ float gelu_fast(float x) {
    const float p = fmaf(0.044715f * x * x, x, x);              // mul, fma
    const float z = __builtin_amdgcn_exp2f(2.3022150322f * p);  // mul, exp2
    const float r = __builtin_amdgcn_rcpf(z + 1.0f);            // add, rcp
    return fmaf(-x, r, x);                                      // fma
}

// pack 2 floats -> 1 u32 of 2 bf16 (emits v_cvt_pk_bf16_f32)
__device__ __forceinline__ unsigned pk2bf(float lo, float hi) {
    __hip_bfloat162 t = __float22bfloat162_rn(make_float2(lo, hi));
    unsigned u; __builtin_memcpy(&u, &t, 4);
    return u;
}

// butterfly sum over each 16-lane row via DPP (xor 1,2,4,8)
__device__ __forceinline__ float row_sum16(float x) {
    int t;
    t = __builtin_amdgcn_update_dpp(0, __float_as_int(x), 0xB1, 0xF, 0xF, true); // xor1
    x += __int_as_float(t);
    t = __builtin_amdgcn_update_dpp(0, __float_as_int(x), 0x4E, 0xF, 0xF, true); // xor2
    x += __int_as_float(t);
    t = __builtin_amdgcn_update_dpp(0, __float_as_int(x), 0x141, 0xF, 0xF, true); // xor4
    x += __int_as_float(t);
    t = __builtin_amdgcn_update_dpp(0, __float_as_int(x), 0x140, 0xF, 0xF, true); // xor8
    x += __int_as_float(t);
    return x;
}

// ---------------------------------------------------------------------------
// FUSED kernel: workgroup = (blk, b) 16x16 pair-block of batch b.
// blk 0..5 strictly-upper (ib<jb), blk 6..9 diagonal (p<=pj; p==pj stores 0).
//
// Prologue (replaces the separate k1 launch + u/v global round-trip; round-9
// accounting showed ~10us of launch/gap overhead on two ~2/~16us kernels):
//   wave 0: u-tile = bf16(e) @ bf16(W1[:64]) + b1 for the 16 i-tokens -> us[][]
//   wave 1: v-tile = bf16(e) @ bf16(W1[64:])        for the 16 j-tokens -> vs[][]
//   (W1 frags from stride-64 scalar loads, L1-hot; e gathered per-lane from
//    the embedding tables; 8 MFMAs each; C/D row=g*4+reg -> LDS row, 2-way
//    bank aliasing on the scalar writes = free.)
//   all waves: B-frags for layer 2 straight from raw W2 (same stride-64
//   scalar-load pattern, no w2t workspace), b2/W3/b3 frags.
// One __syncthreads, then the round-9 body: per (tt, wave) column pj,
// A-frags built in-register with 7-slot gelu, 8 MFMAs, layer-3 gelu + W3
// dot + DPP row-sum, mirrored store. LDS values are bit-identical to the
// round-9 u/v, so numerics are unchanged.
// ---------------------------------------------------------------------------
__global__ __launch_bounds__(256) void k_fused(
    const int* __restrict__ positions, const int* __restrict__ amino,
    const float* __restrict__ pos_table, const float* __restrict__ aa_table,
    const float* __restrict__ W1, const float* __restrict__ b1,
    const float* __restrict__ W2, const float* __restrict__ b2,
    const float* __restrict__ W3, const float* __restrict__ b3,
    float* __restrict__ out)
{
    __shared__ __align__(16) float us[16][UVP];
    __shared__ __align__(16) float vs[16][UVP];
    const int lane = threadIdx.x & 63;
    const int wave = threadIdx.x >> 6;
    const int r = lane & 15;        // A row (build) / C col (output feature)
    const int g = lane >> 4;        // k-group

    const int blk = blockIdx.x;     // 0..9
    const int b   = blockIdx.y;     // 0..127
    // packed (ib, jb) tables: blocks {01,02,03,12,13,23, 00,11,22,33}
    const int ib = (0x1A211200u >> (3 * blk)) & 7;
    const int jb = (0x1A21B4D1u >> (3 * blk)) & 7;
    const bool diag = (blk >= 6);

    // ---- B-frags for layer 2 (all waves): W2[k=kh*32+g*8+e][n=cb*16+r] ----
    bf16x8 bfr[2][4];
#pragma unroll
    for (int kh = 0; kh < 2; ++kh)
#pragma unroll
        for (int cb = 0; cb < 4; ++cb) {
            const float* src = W2 + (kh * 32 + g * 8) * DD + cb * 16 + r;
            float t[8];
#pragma unroll
            for (int e = 0; e < 8; ++e) t[e] = src[e * DD];
            union { bf16x8 v8; unsigned u4[4]; } cvt;
            cvt.u4[0] = pk2bf(t[0], t[1]); cvt.u4[1] = pk2bf(t[2], t[3]);
            cvt.u4[2] = pk2bf(t[4], t[5]); cvt.u4[3] = pk2bf(t[6], t[7]);
            bfr[kh][cb] = cvt.v8;
        }
    float b2f[4], w3f[4];
#pragma unroll
    for (int cb = 0; cb < 4; ++cb) {
        b2f[cb] = b2[cb * 16 + r];
        w3f[cb] = W3[cb * 16 + r];
    }
    const float b3s = b3[0];

    // ---- prologue: wave 0 -> us (u half, +b1), wave 1 -> vs (v half) ----
    if (wave < 2) {
        const int uv = wave;
        const int tb = uv ? jb : ib;             // token tile for this half

        // W1 frags: W1[uv*64 + kh*32 + g*8 + e][cb*16 + r]
        bf16x8 w1f[2][4];
#pragma unroll
        for (int kh = 0; kh < 2; ++kh)
#pragma unroll
            for (int cb = 0; cb < 4; ++cb) {
                const float* src = W1 + (uv * DD + kh * 32 + g * 8) * DD + cb * 16 + r;
                float t[8];
#pragma unroll
                for (int e = 0; e < 8; ++e) t[e] = src[e * DD];
                union { bf16x8 v8; unsigned u4[4]; } cvt;
                cvt.u4[0] = pk2bf(t[0], t[1]); cvt.u4[1] = pk2bf(t[2], t[3]);
                cvt.u4[2] = pk2bf(t[4], t[5]); cvt.u4[3] = pk2bf(t[6], t[7]);
                w1f[kh][cb] = cvt.v8;
            }
        float b1f[4] = {0.0f, 0.0f, 0.0f, 0.0f};
        if (!uv) {
#pragma unroll
            for (int cb = 0; cb < 4; ++cb) b1f[cb] = b1[cb * 16 + r];
        }

        // token gather: this lane's A-row token = tb*16 + r
        const int tok = b * MM + tb * 16 + r;
        int p = positions[tok];
        p = p < 0 ? 0 : (p > PP - 1 ? PP - 1 : p);
        int a = amino[tok];
        a = a < 0 ? 0 : (a > AN - 1 ? AN - 1 : a);

        bf16x8 ef[2];
#pragma unroll
        for (int kh = 0; kh < 2; ++kh) {
            const int koff = kh * 32 + g * 8;
            const float4 p0 = *(const float4*)(pos_table + p * DD + koff);
            const float4 p1 = *(const float4*)(pos_table + p * DD + koff + 4);
            const float4 a0 = *(const float4*)(aa_table + a * DD + koff);
            const float4 a1 = *(const float4*)(aa_table + a * DD + koff + 4);
            union { bf16x8 v8; unsigned u4[4]; } cvt;
            cvt.u4[0] = pk2bf(p0.x + a0.x, p0.y + a0.y);
            cvt.u4[1] = pk2bf(p0.z + a0.z, p0.w + a0.w);
            cvt.u4[2] = pk2bf(p1.x + a1.x, p1.y + a1.y);
            cvt.u4[3] = pk2bf(p1.z + a1.z, p1.w + a1.w);
            ef[kh] = cvt.v8;
        }

        float (* __restrict__ dst)[UVP] = uv ? vs : us;
#pragma unroll
        for (int cb = 0; cb < 4; ++cb) {
            f32x4 z = {0.0f, 0.0f, 0.0f, 0.0f};
            z = __builtin_amdgcn_mfma_f32_16x16x32_bf16(ef[0], w1f[0][cb], z, 0, 0, 0);
            z = __builtin_amdgcn_mfma_f32_16x16x32_bf16(ef[1], w1f[1][cb], z, 0, 0, 0);
            // C/D: row = g*4+reg (token-in-tile), col = cb*16+r (feature)
#pragma unroll
            for (int reg = 0; reg < 4; ++reg)
                dst[g * 4 + reg][cb * 16 + r] = z[reg] + b1f[cb];
        }
    }

    __syncthreads();

    float* __restrict__ ob = out + b * (MM * MM);
    const int i0 = ib * 16;

#pragma unroll
    for (int tt = 0; tt < 4; ++tt) {
        const int pj = tt * 4 + wave;            // column within block
        const int jg = jb * 16 + pj;             // global j

        // ---- layer 1: A frags from LDS ----
        bf16x8 afr[2];
#pragma unroll
        for (int kh = 0; kh < 2; ++kh) {
            const int koff = kh * 32 + g * 8;
            const float4 u0 = *(const float4*)&us[r][koff];
            const float4 u1 = *(const float4*)&us[r][koff + 4];
            const float4 v0 = *(const float4*)&vs[pj][koff];
            const float4 v1 = *(const float4*)&vs[pj][koff + 4];
            float x[8];
            x[0] = u0.x + v0.x; x[1] = u0.y + v0.y; x[2] = u0.z + v0.z; x[3] = u0.w + v0.w;
            x[4] = u1.x + v1.x; x[5] = u1.y + v1.y; x[6] = u1.z + v1.z; x[7] = u1.w + v1.w;
            unsigned w0 = pk2bf(gelu_fast(x[0]), gelu_fast(x[1]));
            unsigned w1 = pk2bf(gelu_fast(x[2]), gelu_fast(x[3]));
            unsigned w2 = pk2bf(gelu_fast(x[4]), gelu_fast(x[5]));
            unsigned w3 = pk2bf(gelu_fast(x[6]), gelu_fast(x[7]));
            union { bf16x8 v8; unsigned u4[4]; } cvt;
            cvt.u4[0] = w0; cvt.u4[1] = w1; cvt.u4[2] = w2; cvt.u4[3] = w3;
            afr[kh] = cvt.v8;
        }

        // ---- layer 2: 8 MFMAs ----
        f32x4 acc[4];
#pragma unroll
        for (int cb = 0; cb < 4; ++cb) {
            f32x4 z = {0.0f, 0.0f, 0.0f, 0.0f};
            z = __builtin_amdgcn_mfma_f32_16x16x32_bf16(afr[0], bfr[0][cb], z, 0, 0, 0);
            acc[cb] = __builtin_amdgcn_mfma_f32_16x16x32_bf16(afr[1], bfr[1][cb], z, 0, 0, 0);
        }

        // ---- layer 3: gelu + W3 dot, DPP row-sum ----
        float s0, s1, s2, s3;
        {
            float a0 = 0, a1 = 0, a2 = 0, a3 = 0;
#pragma unroll
            for (int cb = 0; cb < 4; ++cb) {
                a0 = fmaf(gelu_fast(acc[cb][0] + b2f[cb]), w3f[cb], a0);
                a1 = fmaf(gelu_fast(acc[cb][1] + b2f[cb]), w3f[cb], a1);
                a2 = fmaf(gelu_fast(acc[cb][2] + b2f[cb]), w3f[cb], a2);
                a3 = fmaf(gelu_fast(acc[cb][3] + b2f[cb]), w3f[cb], a3);
            }
            s0 = row_sum16(a0) + b3s;
            s1 = row_sum16(a1) + b3s;
            s2 = row_sum16(a2) + b3s;
            s3 = row_sum16(a3) + b3s;
        }

        if (r < 4) {
            const int p = g * 4 + r;             // local pair (C row)
            if (!diag || p <= pj) {
                float sc = (r == 0) ? s0 : (r == 1) ? s1 : (r == 2) ? s2 : s3;
                if (diag && p == pj) sc = 0.0f;  // diagonal (was k1's job)
                const int ig = i0 + p;
                ob[ig * MM + jg] = sc;           // column (scattered)
                ob[jg * MM + ig] = sc;           // mirror row (coalesced)
            }
        }
    }
}

extern "C" void kernel_launch(void* const* d_in, const int* in_sizes, int n_in,
                              void* d_out, int out_size, void* d_ws, size_t ws_size,
                              hipStream_t stream) {
    const int*   positions = (const int*)  d_in[0];
    const int*   amino     = (const int*)  d_in[1];
    const float* pos_table = (const float*)d_in[2];
    const float* aa_table  = (const float*)d_in[3];
    const float* W1        = (const float*)d_in[4];
    const float* b1        = (const float*)d_in[5];
    const float* W2        = (const float*)d_in[6];
    const float* b2        = (const float*)d_in[7];
    const float* W3        = (const float*)d_in[8];
    const float* b3        = (const float*)d_in[9];
    float* out = (float*)d_out;

    // Single fused launch: (10 pair-blocks) x (128 batches), 256 threads.
    // No workspace, no intermediate u/v round-trip, no second launch.
    k_fused<<<dim3(10, 128), 256, 0, stream>>>(positions, amino, pos_table,
                                               aa_table, W1, b1, W2, b2, W3, b3,
                                               out);
}

// Round 11
// 25.335 us; speedup vs baseline: 2.8702x; 1.1145x over previous
//
#include <hip/hip_runtime.h>
#include <hip/hip_bf16.h>
#include <cmath>

// Problem constants
#define BB 128
#define MM 64
#define DD 64
#define PP 1024
#define AN 21
#define UVP 68                          // padded u/v LDS row stride

typedef __attribute__((ext_vector_type(8))) short bf16x8;   // 8 bf16 = 4 VGPRs
typedef __attribute__((ext_vector_type(4))) float f32x4;    // MFMA C/D

// tanh-approx GELU, 7 issue slots (2 trans):
// gelu = x - x*rcp(exp2(2c*log2e*(x+0.044715x^3)) + 1)
__device__ __forceinline__ float gelu_fast(float x) {
    const float p = fmaf(0.044715f * x * x, x, x);              // mul, fma
    const float z = __builtin_amdgcn_exp2f(2.3022150322f * p);  // mul, exp2
    const float r = __builtin_amdgcn_rcpf(z + 1.0f);            // add, rcp
    return fmaf(-x, r, x);                                      // fma
}

// pack 2 floats -> 1 u32 of 2 bf16 (emits v_cvt_pk_bf16_f32)
__device__ __forceinline__ unsigned pk2bf(float lo, float hi) {
    __hip_bfloat162 t = __float22bfloat162_rn(make_float2(lo, hi));
    unsigned u; __builtin_memcpy(&u, &t, 4);
    return u;
}

// butterfly sum over each 16-lane row via DPP (xor 1,2,4,8)
__device__ __forceinline__ float row_sum16(float x) {
    int t;
    t = __builtin_amdgcn_update_dpp(0, __float_as_int(x), 0xB1, 0xF, 0xF, true); // xor1
    x += __int_as_float(t);
    t = __builtin_amdgcn_update_dpp(0, __float_as_int(x), 0x4E, 0xF, 0xF, true); // xor2
    x += __int_as_float(t);
    t = __builtin_amdgcn_update_dpp(0, __float_as_int(x), 0x141, 0xF, 0xF, true); // xor4
    x += __int_as_float(t);
    t = __builtin_amdgcn_update_dpp(0, __float_as_int(x), 0x140, 0xF, 0xF, true); // xor8
    x += __int_as_float(t);
    return x;
}

// ---------------------------------------------------------------------------
// FUSED kernel, diagonal-packed. Grid (8, 128) = 1024 WGs (4 WG/CU exactly).
// blk 0..5: strictly-upper 16x16 blocks (ib<jb) -- as round 10.
// blk 6..7: TWO diagonal triangles d0=2(blk-6), d1=d0+1 packed per WG:
//   column-slot s (=tt*4+wave, 1..15; slot 0 duplicates s=8, benign
//   identical stores): lane r<s -> pair (r, s) of d0; lane r>=s ->
//   pair (r-s, 16-s) of d1. 15 slots cover both triangles with ZERO masked
//   rows (round 10's diag blocks wasted 21% of all column-slots on masked
//   rows). Each lane builds its A-row from per-lane-selected LDS tiles, so
//   mixed-triangle columns cost only 2 cndmask'd base pointers per slot.
// Prologue: tiles[4] = {u(lo), v(lo), u(hi), v(hi)} -- one wave each for
// packed blocks; waves 0,1 -> u(ib), v(jb) for off-diag.
// Packed blocks also zero their 32 out-diagonal entries.
// ---------------------------------------------------------------------------
__global__ __launch_bounds__(256) void k_fused(
    const int* __restrict__ positions, const int* __restrict__ amino,
    const float* __restrict__ pos_table, const float* __restrict__ aa_table,
    const float* __restrict__ W1, const float* __restrict__ b1,
    const float* __restrict__ W2, const float* __restrict__ b2,
    const float* __restrict__ W3, const float* __restrict__ b3,
    float* __restrict__ out)
{
    __shared__ __align__(16) float tiles[4][16][UVP];
    const int lane = threadIdx.x & 63;
    const int wave = threadIdx.x >> 6;
    const int r = lane & 15;        // A row (build) / C col (output feature)
    const int g = lane >> 4;        // k-group

    const int blk = blockIdx.x;     // 0..7
    const int b   = blockIdx.y;     // 0..127
    const bool packed = (blk >= 6);
    // off-diag (ib, jb) tables, 3 bits each: blocks {01,02,03,12,13,23}
    const int ib = (0x11200u >> (3 * blk)) & 7;
    const int jb = (0x1B4D1u >> (3 * blk)) & 7;
    const int dlo = packed ? 2 * (blk - 6) : 0;     // packed triangle tiles
    const int dhi = dlo + 1;

    // ---- B-frags for layer 2 (all waves): W2[k=kh*32+g*8+e][n=cb*16+r] ----
    bf16x8 bfr[2][4];
#pragma unroll
    for (int kh = 0; kh < 2; ++kh)
#pragma unroll
        for (int cb = 0; cb < 4; ++cb) {
            const float* src = W2 + (kh * 32 + g * 8) * DD + cb * 16 + r;
            float t[8];
#pragma unroll
            for (int e = 0; e < 8; ++e) t[e] = src[e * DD];
            union { bf16x8 v8; unsigned u4[4]; } cvt;
            cvt.u4[0] = pk2bf(t[0], t[1]); cvt.u4[1] = pk2bf(t[2], t[3]);
            cvt.u4[2] = pk2bf(t[4], t[5]); cvt.u4[3] = pk2bf(t[6], t[7]);
            bfr[kh][cb] = cvt.v8;
        }
    float b2f[4], w3f[4];
#pragma unroll
    for (int cb = 0; cb < 4; ++cb) {
        b2f[cb] = b2[cb * 16 + r];
        w3f[cb] = W3[cb * 16 + r];
    }
    const float b3s = b3[0];

    float* __restrict__ ob = out + b * (MM * MM);

    // ---- prologue: compute u/v tiles into LDS ----
    // off-diag: wave0 -> tiles[0]=u(ib), wave1 -> tiles[1]=v(jb).
    // packed:   wave w -> tiles[w] = {u(dlo), v(dlo), u(dhi), v(dhi)}.
    if (packed || wave < 2) {
        const int uv = wave & 1;
        const int tb = packed ? (dlo + (wave >> 1)) : (uv ? jb : ib);

        // W1 frags: W1[uv*64 + kh*32 + g*8 + e][cb*16 + r]
        bf16x8 w1f[2][4];
#pragma unroll
        for (int kh = 0; kh < 2; ++kh)
#pragma unroll
            for (int cb = 0; cb < 4; ++cb) {
                const float* src = W1 + (uv * DD + kh * 32 + g * 8) * DD + cb * 16 + r;
                float t[8];
#pragma unroll
                for (int e = 0; e < 8; ++e) t[e] = src[e * DD];
                union { bf16x8 v8; unsigned u4[4]; } cvt;
                cvt.u4[0] = pk2bf(t[0], t[1]); cvt.u4[1] = pk2bf(t[2], t[3]);
                cvt.u4[2] = pk2bf(t[4], t[5]); cvt.u4[3] = pk2bf(t[6], t[7]);
                w1f[kh][cb] = cvt.v8;
            }
        float b1f[4] = {0.0f, 0.0f, 0.0f, 0.0f};
        if (!uv) {
#pragma unroll
            for (int cb = 0; cb < 4; ++cb) b1f[cb] = b1[cb * 16 + r];
        }

        // token gather: this lane's A-row token = tb*16 + r
        const int tok = b * MM + tb * 16 + r;
        int p = positions[tok];
        p = p < 0 ? 0 : (p > PP - 1 ? PP - 1 : p);
        int a = amino[tok];
        a = a < 0 ? 0 : (a > AN - 1 ? AN - 1 : a);

        bf16x8 ef[2];
#pragma unroll
        for (int kh = 0; kh < 2; ++kh) {
            const int koff = kh * 32 + g * 8;
            const float4 p0 = *(const float4*)(pos_table + p * DD + koff);
            const float4 p1 = *(const float4*)(pos_table + p * DD + koff + 4);
            const float4 a0 = *(const float4*)(aa_table + a * DD + koff);
            const float4 a1 = *(const float4*)(aa_table + a * DD + koff + 4);
            union { bf16x8 v8; unsigned u4[4]; } cvt;
            cvt.u4[0] = pk2bf(p0.x + a0.x, p0.y + a0.y);
            cvt.u4[1] = pk2bf(p0.z + a0.z, p0.w + a0.w);
            cvt.u4[2] = pk2bf(p1.x + a1.x, p1.y + a1.y);
            cvt.u4[3] = pk2bf(p1.z + a1.z, p1.w + a1.w);
            ef[kh] = cvt.v8;
        }

        float (* __restrict__ dst)[UVP] = tiles[wave];
#pragma unroll
        for (int cb = 0; cb < 4; ++cb) {
            f32x4 z = {0.0f, 0.0f, 0.0f, 0.0f};
            z = __builtin_amdgcn_mfma_f32_16x16x32_bf16(ef[0], w1f[0][cb], z, 0, 0, 0);
            z = __builtin_amdgcn_mfma_f32_16x16x32_bf16(ef[1], w1f[1][cb], z, 0, 0, 0);
            // C/D: row = g*4+reg (token-in-tile), col = cb*16+r (feature)
#pragma unroll
            for (int reg = 0; reg < 4; ++reg)
                dst[g * 4 + reg][cb * 16 + r] = z[reg] + b1f[cb];
        }
    }

    // diagonal zeros (formerly k1's job): packed WGs own tokens dlo*16..+31
    if (packed && threadIdx.x < 32) {
        const int m = dlo * 16 + threadIdx.x;
        ob[m * (MM + 1)] = 0.0f;
    }

    __syncthreads();

#pragma unroll
    for (int tt = 0; tt < 4; ++tt) {
        const int ss = tt * 4 + wave;            // column-slot 0..15

        // per-lane LDS row selection for the A-build
        const float* up;                         // u-row (this lane's i)
        const float* vp;                         // v-row (this lane's j)
        int s = ss;
        if (packed) {
            s = ss ? ss : 8;                     // slot 0 duplicates slot 8
            const bool lo = r < s;
            up = lo ? &tiles[0][r][0]     : &tiles[2][r - s][0];
            vp = lo ? &tiles[1][s][0]     : &tiles[3][16 - s][0];
        } else {
            up = &tiles[0][r][0];
            vp = &tiles[1][ss][0];
        }

        // ---- layer 1: A frags from LDS ----
        bf16x8 afr[2];
#pragma unroll
        for (int kh = 0; kh < 2; ++kh) {
            const int koff = kh * 32 + g * 8;
            const float4 u0 = *(const float4*)(up + koff);
            const float4 u1 = *(const float4*)(up + koff + 4);
            const float4 v0 = *(const float4*)(vp + koff);
            const float4 v1 = *(const float4*)(vp + koff + 4);
            float x[8];
            x[0] = u0.x + v0.x; x[1] = u0.y + v0.y; x[2] = u0.z + v0.z; x[3] = u0.w + v0.w;
            x[4] = u1.x + v1.x; x[5] = u1.y + v1.y; x[6] = u1.z + v1.z; x[7] = u1.w + v1.w;
            unsigned w0 = pk2bf(gelu_fast(x[0]), gelu_fast(x[1]));
            unsigned w1 = pk2bf(gelu_fast(x[2]), gelu_fast(x[3]));
            unsigned w2 = pk2bf(gelu_fast(x[4]), gelu_fast(x[5]));
            unsigned w3 = pk2bf(gelu_fast(x[6]), gelu_fast(x[7]));
            union { bf16x8 v8; unsigned u4[4]; } cvt;
            cvt.u4[0] = w0; cvt.u4[1] = w1; cvt.u4[2] = w2; cvt.u4[3] = w3;
            afr[kh] = cvt.v8;
        }

        // ---- layer 2: 8 MFMAs ----
        f32x4 acc[4];
#pragma unroll
        for (int cb = 0; cb < 4; ++cb) {
            f32x4 z = {0.0f, 0.0f, 0.0f, 0.0f};
            z = __builtin_amdgcn_mfma_f32_16x16x32_bf16(afr[0], bfr[0][cb], z, 0, 0, 0);
            acc[cb] = __builtin_amdgcn_mfma_f32_16x16x32_bf16(afr[1], bfr[1][cb], z, 0, 0, 0);
        }

        // ---- layer 3: gelu + W3 dot, DPP row-sum ----
        float s0, s1, s2, s3;
        {
            float a0 = 0, a1 = 0, a2 = 0, a3 = 0;
#pragma unroll
            for (int cb = 0; cb < 4; ++cb) {
                a0 = fmaf(gelu_fast(acc[cb][0] + b2f[cb]), w3f[cb], a0);
                a1 = fmaf(gelu_fast(acc[cb][1] + b2f[cb]), w3f[cb], a1);
                a2 = fmaf(gelu_fast(acc[cb][2] + b2f[cb]), w3f[cb], a2);
                a3 = fmaf(gelu_fast(acc[cb][3] + b2f[cb]), w3f[cb], a3);
            }
            s0 = row_sum16(a0) + b3s;
            s1 = row_sum16(a1) + b3s;
            s2 = row_sum16(a2) + b3s;
            s3 = row_sum16(a3) + b3s;
        }

        // ---- store: lane (g, r<4) owns C row p = g*4+r of this column ----
        if (r < 4) {
            const int p = g * 4 + r;
            const float sc = (r == 0) ? s0 : (r == 1) ? s1 : (r == 2) ? s2 : s3;
            int ig, jg;
            if (packed) {
                const bool lo = p < s;
                ig = lo ? dlo * 16 + p : dhi * 16 + (p - s);
                jg = lo ? dlo * 16 + s : dhi * 16 + (16 - s);
            } else {
                ig = ib * 16 + p;
                jg = jb * 16 + ss;
            }
            ob[ig * MM + jg] = sc;               // column (scattered)
            ob[jg * MM + ig] = sc;               // mirror row (coalesced)
        }
    }
}

extern "C" void kernel_launch(void* const* d_in, const int* in_sizes, int n_in,
                              void* d_out, int out_size, void* d_ws, size_t ws_size,
                              hipStream_t stream) {
    const int*   positions = (const int*)  d_in[0];
    const int*   amino     = (const int*)  d_in[1];
    const float* pos_table = (const float*)d_in[2];
    const float* aa_table  = (const float*)d_in[3];
    const float* W1        = (const float*)d_in[4];
    const float* b1        = (const float*)d_in[5];
    const float* W2        = (const float*)d_in[6];
    const float* b2        = (const float*)d_in[7];
    const float* W3        = (const float*)d_in[8];
    const float* b3        = (const float*)d_in[9];
    float* out = (float*)d_out;

    // Single fused launch: (6 off-diag + 2 packed-diag) x 128 batches.
    k_fused<<<dim3(8, 128), 256, 0, stream>>>(positions, amino, pos_table,
                                              aa_table, W1, b1, W2, b2, W3, b3,
                                              out);
}

// Round 12
// 24.297 us; speedup vs baseline: 2.9927x; 1.0427x over previous
//
#include <hip/hip_runtime.h>
#include <hip/hip_bf16.h>
#include <cmath>

// Problem constants
#define BB 128
#define MM 64
#define DD 64
#define PP 1024
#define AN 21
#define UVP 68                          // padded u/v LDS row stride

typedef __attribute__((ext_vector_type(8))) short bf16x8;   // 8 bf16 = 4 VGPRs
typedef __attribute__((ext_vector_type(4))) float f32x4;    // MFMA C/D + pk math
typedef __attribute__((ext_vector_type(2))) float f32x2;    // v_pk_*_f32 pairs

// paired tanh-approx GELU: 6 packed-f32 VALU (v_pk_mul/add/fma) + 4 trans
// per TWO gelus (vs 14 VALU + 4 trans scalar). Same approximation as the
// scalar 7-slot version, re-associated: x + c x^3 == x*(1 + c x^2).
__device__ __forceinline__ f32x2 gelu2(f32x2 x) {
    const f32x2 x2 = x * x;                                        // pk_mul
    const f32x2 q  = __builtin_elementwise_fma(
        x2, (f32x2){0.044715f, 0.044715f}, (f32x2){1.0f, 1.0f});   // pk_fma
    const f32x2 p  = x * q;                                        // pk_mul
    const f32x2 zm = p * (f32x2){2.3022150322f, 2.3022150322f};    // pk_mul
    f32x2 z;
    z[0] = __builtin_amdgcn_exp2f(zm[0]);                          // trans
    z[1] = __builtin_amdgcn_exp2f(zm[1]);                          // trans
    const f32x2 zp = z + (f32x2){1.0f, 1.0f};                      // pk_add
    f32x2 r;
    r[0] = __builtin_amdgcn_rcpf(zp[0]);                           // trans
    r[1] = __builtin_amdgcn_rcpf(zp[1]);                           // trans
    return __builtin_elementwise_fma(-x, r, x);                    // pk_fma
}

// pack 2 floats -> 1 u32 of 2 bf16 (emits v_cvt_pk_bf16_f32)
__device__ __forceinline__ unsigned pk2bf(float lo, float hi) {
    __hip_bfloat162 t = __float22bfloat162_rn(make_float2(lo, hi));
    unsigned u; __builtin_memcpy(&u, &t, 4);
    return u;
}

// butterfly sum over each 16-lane row via DPP (xor 1,2,4,8)
__device__ __forceinline__ float row_sum16(float x) {
    int t;
    t = __builtin_amdgcn_update_dpp(0, __float_as_int(x), 0xB1, 0xF, 0xF, true); // xor1
    x += __int_as_float(t);
    t = __builtin_amdgcn_update_dpp(0, __float_as_int(x), 0x4E, 0xF, 0xF, true); // xor2
    x += __int_as_float(t);
    t = __builtin_amdgcn_update_dpp(0, __float_as_int(x), 0x141, 0xF, 0xF, true); // xor4
    x += __int_as_float(t);
    t = __builtin_amdgcn_update_dpp(0, __float_as_int(x), 0x140, 0xF, 0xF, true); // xor8
    x += __int_as_float(t);
    return x;
}

// ---------------------------------------------------------------------------
// FUSED kernel, diagonal-packed (round-11 structure) + packed-f32 VALU.
// Grid (8, 128) = 1024 WGs (4 WG/CU).
// blk 0..5: strictly-upper 16x16 blocks (ib<jb).
// blk 6..7: two diagonal triangles packed per WG via column-slot scheme
//   (slot s: lanes r<s -> pair (r,s) of d0; r>=s -> (r-s, 16-s) of d1;
//    slot 0 duplicates slot 8 -- benign identical stores).
// Prologue: u/v tiles MFMA'd into LDS (one wave per tile); W2/W1 fragments
// from stride-64 scalar loads (L1-hot); all f32 elementwise math in
// f32x2/f32x4 ext-vectors -> v_pk_*_f32 dual-issue ops.
// ---------------------------------------------------------------------------
__global__ __launch_bounds__(256) void k_fused(
    const int* __restrict__ positions, const int* __restrict__ amino,
    const float* __restrict__ pos_table, const float* __restrict__ aa_table,
    const float* __restrict__ W1, const float* __restrict__ b1,
    const float* __restrict__ W2, const float* __restrict__ b2,
    const float* __restrict__ W3, const float* __restrict__ b3,
    float* __restrict__ out)
{
    __shared__ __align__(16) float tiles[4][16][UVP];
    const int lane = threadIdx.x & 63;
    const int wave = threadIdx.x >> 6;
    const int r = lane & 15;        // A row (build) / C col (output feature)
    const int g = lane >> 4;        // k-group

    const int blk = blockIdx.x;     // 0..7
    const int b   = blockIdx.y;     // 0..127
    const bool packed = (blk >= 6);
    // off-diag (ib, jb) tables, 3 bits each: blocks {01,02,03,12,13,23}
    const int ib = (0x11200u >> (3 * blk)) & 7;
    const int jb = (0x1B4D1u >> (3 * blk)) & 7;
    const int dlo = packed ? 2 * (blk - 6) : 0;     // packed triangle tiles
    const int dhi = dlo + 1;

    // ---- B-frags for layer 2 (all waves): W2[k=kh*32+g*8+e][n=cb*16+r] ----
    bf16x8 bfr[2][4];
#pragma unroll
    for (int kh = 0; kh < 2; ++kh)
#pragma unroll
        for (int cb = 0; cb < 4; ++cb) {
            const float* src = W2 + (kh * 32 + g * 8) * DD + cb * 16 + r;
            float t[8];
#pragma unroll
            for (int e = 0; e < 8; ++e) t[e] = src[e * DD];
            union { bf16x8 v8; unsigned u4[4]; } cvt;
            cvt.u4[0] = pk2bf(t[0], t[1]); cvt.u4[1] = pk2bf(t[2], t[3]);
            cvt.u4[2] = pk2bf(t[4], t[5]); cvt.u4[3] = pk2bf(t[6], t[7]);
            bfr[kh][cb] = cvt.v8;
        }
    float b2f[4], w3f[4];
#pragma unroll
    for (int cb = 0; cb < 4; ++cb) {
        b2f[cb] = b2[cb * 16 + r];
        w3f[cb] = W3[cb * 16 + r];
    }
    const float b3s = b3[0];

    float* __restrict__ ob = out + b * (MM * MM);

    // ---- prologue: compute u/v tiles into LDS ----
    // off-diag: wave0 -> tiles[0]=u(ib), wave1 -> tiles[1]=v(jb).
    // packed:   wave w -> tiles[w] = {u(dlo), v(dlo), u(dhi), v(dhi)}.
    if (packed || wave < 2) {
        const int uv = wave & 1;
        const int tb = packed ? (dlo + (wave >> 1)) : (uv ? jb : ib);

        // W1 frags: W1[uv*64 + kh*32 + g*8 + e][cb*16 + r]
        bf16x8 w1f[2][4];
#pragma unroll
        for (int kh = 0; kh < 2; ++kh)
#pragma unroll
            for (int cb = 0; cb < 4; ++cb) {
                const float* src = W1 + (uv * DD + kh * 32 + g * 8) * DD + cb * 16 + r;
                float t[8];
#pragma unroll
                for (int e = 0; e < 8; ++e) t[e] = src[e * DD];
                union { bf16x8 v8; unsigned u4[4]; } cvt;
                cvt.u4[0] = pk2bf(t[0], t[1]); cvt.u4[1] = pk2bf(t[2], t[3]);
                cvt.u4[2] = pk2bf(t[4], t[5]); cvt.u4[3] = pk2bf(t[6], t[7]);
                w1f[kh][cb] = cvt.v8;
            }
        float b1f[4] = {0.0f, 0.0f, 0.0f, 0.0f};
        if (!uv) {
#pragma unroll
            for (int cb = 0; cb < 4; ++cb) b1f[cb] = b1[cb * 16 + r];
        }

        // token gather: this lane's A-row token = tb*16 + r
        const int tok = b * MM + tb * 16 + r;
        int p = positions[tok];
        p = p < 0 ? 0 : (p > PP - 1 ? PP - 1 : p);
        int a = amino[tok];
        a = a < 0 ? 0 : (a > AN - 1 ? AN - 1 : a);

        bf16x8 ef[2];
#pragma unroll
        for (int kh = 0; kh < 2; ++kh) {
            const int koff = kh * 32 + g * 8;
            const f32x4 p0 = *(const f32x4*)(pos_table + p * DD + koff);
            const f32x4 p1 = *(const f32x4*)(pos_table + p * DD + koff + 4);
            const f32x4 a0 = *(const f32x4*)(aa_table + a * DD + koff);
            const f32x4 a1 = *(const f32x4*)(aa_table + a * DD + koff + 4);
            const f32x4 e0 = p0 + a0;           // v_pk_add_f32 x2
            const f32x4 e1 = p1 + a1;
            union { bf16x8 v8; unsigned u4[4]; } cvt;
            cvt.u4[0] = pk2bf(e0[0], e0[1]);
            cvt.u4[1] = pk2bf(e0[2], e0[3]);
            cvt.u4[2] = pk2bf(e1[0], e1[1]);
            cvt.u4[3] = pk2bf(e1[2], e1[3]);
            ef[kh] = cvt.v8;
        }

        float (* __restrict__ dst)[UVP] = tiles[wave];
#pragma unroll
        for (int cb = 0; cb < 4; ++cb) {
            f32x4 z = {0.0f, 0.0f, 0.0f, 0.0f};
            z = __builtin_amdgcn_mfma_f32_16x16x32_bf16(ef[0], w1f[0][cb], z, 0, 0, 0);
            z = __builtin_amdgcn_mfma_f32_16x16x32_bf16(ef[1], w1f[1][cb], z, 0, 0, 0);
            // C/D: row = g*4+reg (token-in-tile), col = cb*16+r (feature)
#pragma unroll
            for (int reg = 0; reg < 4; ++reg)
                dst[g * 4 + reg][cb * 16 + r] = z[reg] + b1f[cb];
        }
    }

    // diagonal zeros: packed WGs own tokens dlo*16..+31
    if (packed && threadIdx.x < 32) {
        const int m = dlo * 16 + threadIdx.x;
        ob[m * (MM + 1)] = 0.0f;
    }

    __syncthreads();

#pragma unroll
    for (int tt = 0; tt < 4; ++tt) {
        const int ss = tt * 4 + wave;            // column-slot 0..15

        // per-lane LDS row selection for the A-build
        const float* up;                         // u-row (this lane's i)
        const float* vp;                         // v-row (this lane's j)
        int s = ss;
        if (packed) {
            s = ss ? ss : 8;                     // slot 0 duplicates slot 8
            const bool lo = r < s;
            up = lo ? &tiles[0][r][0]     : &tiles[2][r - s][0];
            vp = lo ? &tiles[1][s][0]     : &tiles[3][16 - s][0];
        } else {
            up = &tiles[0][r][0];
            vp = &tiles[1][ss][0];
        }

        // ---- layer 1: A frags from LDS; pk adds + paired gelu ----
        bf16x8 afr[2];
#pragma unroll
        for (int kh = 0; kh < 2; ++kh) {
            const int koff = kh * 32 + g * 8;
            const f32x4 u0 = *(const f32x4*)(up + koff);
            const f32x4 u1 = *(const f32x4*)(up + koff + 4);
            const f32x4 v0 = *(const f32x4*)(vp + koff);
            const f32x4 v1 = *(const f32x4*)(vp + koff + 4);
            const f32x4 x0 = u0 + v0;            // v_pk_add_f32 x2
            const f32x4 x1 = u1 + v1;
            const f32x2 g0 = gelu2(__builtin_shufflevector(x0, x0, 0, 1));
            const f32x2 g1 = gelu2(__builtin_shufflevector(x0, x0, 2, 3));
            const f32x2 g2 = gelu2(__builtin_shufflevector(x1, x1, 0, 1));
            const f32x2 g3 = gelu2(__builtin_shufflevector(x1, x1, 2, 3));
            union { bf16x8 v8; unsigned u4[4]; } cvt;
            cvt.u4[0] = pk2bf(g0[0], g0[1]);
            cvt.u4[1] = pk2bf(g1[0], g1[1]);
            cvt.u4[2] = pk2bf(g2[0], g2[1]);
            cvt.u4[3] = pk2bf(g3[0], g3[1]);
            afr[kh] = cvt.v8;
        }

        // ---- layer 2: 8 MFMAs ----
        f32x4 acc[4];
#pragma unroll
        for (int cb = 0; cb < 4; ++cb) {
            f32x4 z = {0.0f, 0.0f, 0.0f, 0.0f};
            z = __builtin_amdgcn_mfma_f32_16x16x32_bf16(afr[0], bfr[0][cb], z, 0, 0, 0);
            acc[cb] = __builtin_amdgcn_mfma_f32_16x16x32_bf16(afr[1], bfr[1][cb], z, 0, 0, 0);
        }

        // ---- layer 3: paired gelu + pk W3 fma, DPP row-sum ----
        f32x2 a01 = {0.0f, 0.0f}, a23 = {0.0f, 0.0f};
#pragma unroll
        for (int cb = 0; cb < 4; ++cb) {
            const f32x2 bb = {b2f[cb], b2f[cb]};
            const f32x2 ww = {w3f[cb], w3f[cb]};
            const f32x2 lo = (f32x2){acc[cb][0], acc[cb][1]} + bb;   // pk_add
            const f32x2 hi = (f32x2){acc[cb][2], acc[cb][3]} + bb;
            a01 = __builtin_elementwise_fma(gelu2(lo), ww, a01);     // pk_fma
            a23 = __builtin_elementwise_fma(gelu2(hi), ww, a23);
        }
        const float s0 = row_sum16(a01[0]) + b3s;
        const float s1 = row_sum16(a01[1]) + b3s;
        const float s2 = row_sum16(a23[0]) + b3s;
        const float s3 = row_sum16(a23[1]) + b3s;

        // ---- store: lane (g, r<4) owns C row p = g*4+r of this column ----
        if (r < 4) {
            const int p = g * 4 + r;
            const float sc = (r == 0) ? s0 : (r == 1) ? s1 : (r == 2) ? s2 : s3;
            int ig, jg;
            if (packed) {
                const bool lo = p < s;
                ig = lo ? dlo * 16 + p : dhi * 16 + (p - s);
                jg = lo ? dlo * 16 + s : dhi * 16 + (16 - s);
            } else {
                ig = ib * 16 + p;
                jg = jb * 16 + ss;
            }
            ob[ig * MM + jg] = sc;               // column (scattered)
            ob[jg * MM + ig] = sc;               // mirror row (coalesced)
        }
    }
}

extern "C" void kernel_launch(void* const* d_in, const int* in_sizes, int n_in,
                              void* d_out, int out_size, void* d_ws, size_t ws_size,
                              hipStream_t stream) {
    const int*   positions = (const int*)  d_in[0];
    const int*   amino     = (const int*)  d_in[1];
    const float* pos_table = (const float*)d_in[2];
    const float* aa_table  = (const float*)d_in[3];
    const float* W1        = (const float*)d_in[4];
    const float* b1        = (const float*)d_in[5];
    const float* W2        = (const float*)d_in[6];
    const float* b2        = (const float*)d_in[7];
    const float* W3        = (const float*)d_in[8];
    const float* b3        = (const float*)d_in[9];
    float* out = (float*)d_out;

    // Single fused launch: (6 off-diag + 2 packed-diag) x 128 batches.
    k_fused<<<dim3(8, 128), 256, 0, stream>>>(positions, amino, pos_table,
                                              aa_table, W1, b1, W2, b2, W3, b3,
                                              out);
}